// Round 2
// baseline (204.463 us; speedup 1.0000x reference)
//
#include <hip/hip_runtime.h>
#include <stdint.h>

#define NF 27
#define ND 128
#define OUTW 479          // 128 + 27*26/2
#define LDSROW 136        // 128 + 8 pad (ushort units); 272 B rows -> bank spread
#define WAVES 4

typedef float f32x4 __attribute__((ext_vector_type(4)));
typedef short s16x8 __attribute__((ext_vector_type(8)));

__device__ __forceinline__ unsigned short f2bf(float x) {
    union { float f; uint32_t u; } c; c.f = x;
    uint32_t u = c.u;
    u += 0x7fffu + ((u >> 16) & 1u);   // RNE round to bf16
    return (unsigned short)(u >> 16);
}

__global__ __launch_bounds__(256) void dot_interact_kernel(
    const float* __restrict__ feat,
    const float* __restrict__ bottom,
    float* __restrict__ out, int B)
{
    __shared__ unsigned short smem[WAVES][32 * LDSROW];   // 34,816 B/block
    const int tid  = threadIdx.x;
    const int w    = tid >> 6;
    const int lane = tid & 63;
    const int b    = blockIdx.x * WAVES + w;
    unsigned short* sm = smem[w];

    if (b < B) {
        // ---- stage: 27*128 f32 -> bf16 LDS rows 0..26; rows 27..31 zeroed ----
        const float4* f4 = (const float4*)(feat + (size_t)b * (NF * ND));
        #pragma unroll
        for (int t = 0; t < 16; ++t) {
            int fi  = lane + 64 * t;          // 0..1023 covers 32 rows * 32 float4
            int row = fi >> 5;
            int c4  = fi & 31;
            uint32_t lo = 0, hi = 0;
            if (fi < 864) {                   // 27 rows * 32 float4 of real data
                float4 v = f4[fi];
                lo = (uint32_t)f2bf(v.x) | ((uint32_t)f2bf(v.y) << 16);
                hi = (uint32_t)f2bf(v.z) | ((uint32_t)f2bf(v.w) << 16);
            }
            *(uint2*)(&sm[row * LDSROW + c4 * 4]) = make_uint2(lo, hi);
        }
    }
    __syncthreads();

    // ---- Gram = F * F^T via mfma_f32_16x16x32_bf16 ----
    f32x4 acc00 = {0.f,0.f,0.f,0.f};
    f32x4 acc10 = {0.f,0.f,0.f,0.f};
    f32x4 acc11 = {0.f,0.f,0.f,0.f};
    if (b < B) {
        const int rsel = lane & 15;
        const int ksel = (lane >> 4) * 8;
        #pragma unroll
        for (int ks = 0; ks < 4; ++ks) {
            int k0 = ks * 32 + ksel;
            s16x8 fr0 = *(const s16x8*)(&sm[(rsel     ) * LDSROW + k0]);
            s16x8 fr1 = *(const s16x8*)(&sm[(rsel + 16) * LDSROW + k0]);
            acc00 = __builtin_amdgcn_mfma_f32_16x16x32_bf16(fr0, fr0, acc00, 0, 0, 0);
            acc10 = __builtin_amdgcn_mfma_f32_16x16x32_bf16(fr1, fr0, acc10, 0, 0, 0);
            acc11 = __builtin_amdgcn_mfma_f32_16x16x32_bf16(fr1, fr1, acc11, 0, 0, 0);
        }
    }
    __syncthreads();   // fragment reads complete before LDS region is reused

    if (b >= B) return;

    // ---- assemble full 479-f32 output row in wave-private LDS ----
    float* ow = (float*)sm;                   // 8704 B available, need 1916 B
    const float* bb = bottom + (size_t)b * ND;
    ow[lane]      = bb[lane];
    ow[lane + 64] = bb[lane + 64];

    // tril scatter into LDS: C/D layout col=lane&15, row=(lane>>4)*4+e
    const int jj = lane & 15;
    const int r0 = (lane >> 4) * 4;
    #pragma unroll
    for (int e = 0; e < 4; ++e) {
        int i0 = r0 + e;                       // tile (0,0): i 0..15, j 0..15
        if (jj < i0) ow[128 + (i0 * (i0 - 1)) / 2 + jj] = acc00[e];
        int i1 = i0 + 16;                      // tiles (1,0)/(1,1): i 16..26
        if (i1 < NF) {
            ow[128 + (i1 * (i1 - 1)) / 2 + jj] = acc10[e];          // j 0..15 < i
            int j1 = jj + 16;
            if (j1 < i1) ow[128 + (i1 * (i1 - 1)) / 2 + j1] = acc11[e];
        }
    }

    // ---- coalesced stream-out: 8 x 256B stride-1 stores ----
    float* og = out + (size_t)b * OUTW;
    #pragma unroll
    for (int t = 0; t < 8; ++t) {
        int idx = lane + 64 * t;
        if (idx < OUTW) og[idx] = ow[idx];
    }
}

extern "C" void kernel_launch(void* const* d_in, const int* in_sizes, int n_in,
                              void* d_out, int out_size, void* d_ws, size_t ws_size,
                              hipStream_t stream) {
    const float* feat   = (const float*)d_in[0];
    const float* bottom = (const float*)d_in[1];
    float* out          = (float*)d_out;
    const int B = in_sizes[0] / (NF * ND);
    const int grid = (B + WAVES - 1) / WAVES;
    dot_interact_kernel<<<grid, 256, 0, stream>>>(feat, bottom, out, B);
}

// Round 3
// 200.359 us; speedup vs baseline: 1.0205x; 1.0205x over previous
//
#include <hip/hip_runtime.h>
#include <stdint.h>

#define NF 27
#define ND 128
#define OUTW 479          // 128 + 27*26/2
#define LDSROW 136        // 128 + 8 pad (ushort units); 272 B rows -> uniform bank spread
#define WAVES 4

typedef float f32x4 __attribute__((ext_vector_type(4)));
typedef short s16x8 __attribute__((ext_vector_type(8)));

__device__ __forceinline__ unsigned short f2bf(float x) {
    union { float f; uint32_t u; } c; c.f = x;
    uint32_t u = c.u;
    u += 0x7fffu + ((u >> 16) & 1u);   // RNE round to bf16
    return (unsigned short)(u >> 16);
}

// 27 data rows per wave; +5 row tail pad so wave 3's fr1 reads of "rows 27..31"
// stay inside the block allocation (values are garbage but only feed Gram
// entries with i>=27 or j>=27, which are never stored).
#define ROWS_ALLOC (WAVES * NF * LDSROW + 5 * LDSROW)   // 30,736 B -> 5 blocks/CU

__global__ __launch_bounds__(256) void dot_interact_kernel(
    const float* __restrict__ feat,
    const float* __restrict__ bottom,
    float* __restrict__ out, int B)
{
    __shared__ unsigned short smem[ROWS_ALLOC];
    const int tid  = threadIdx.x;
    const int w    = tid >> 6;
    const int lane = tid & 63;
    const int b    = blockIdx.x * WAVES + w;
    unsigned short* sm = smem + w * (NF * LDSROW);

    if (b < B) {
        // ---- stage: 27*128 f32 -> bf16 LDS (864 float4, 14 wave-iters) ----
        const float4* f4 = (const float4*)(feat + (size_t)b * (NF * ND));
        #pragma unroll
        for (int t = 0; t < 14; ++t) {
            int fi  = lane + 64 * t;
            if (fi < NF * 32) {
                float4 v = f4[fi];
                int row = fi >> 5;
                int c4  = fi & 31;
                uint32_t lo = (uint32_t)f2bf(v.x) | ((uint32_t)f2bf(v.y) << 16);
                uint32_t hi = (uint32_t)f2bf(v.z) | ((uint32_t)f2bf(v.w) << 16);
                *(uint2*)(&sm[row * LDSROW + c4 * 4]) = make_uint2(lo, hi);
            }
        }
    }
    __syncthreads();
    if (b >= B) return;

    // ---- Gram = F * F^T via mfma_f32_16x16x32_bf16 (one frag feeds A and B) ----
    f32x4 acc00 = {0.f,0.f,0.f,0.f};
    f32x4 acc10 = {0.f,0.f,0.f,0.f};
    f32x4 acc11 = {0.f,0.f,0.f,0.f};
    const int rsel = lane & 15;
    const int ksel = (lane >> 4) * 8;
    #pragma unroll
    for (int ks = 0; ks < 4; ++ks) {
        int k0 = ks * 32 + ksel;
        s16x8 fr0 = *(const s16x8*)(&sm[(rsel     ) * LDSROW + k0]);
        s16x8 fr1 = *(const s16x8*)(&sm[(rsel + 16) * LDSROW + k0]);
        acc00 = __builtin_amdgcn_mfma_f32_16x16x32_bf16(fr0, fr0, acc00, 0, 0, 0);
        acc10 = __builtin_amdgcn_mfma_f32_16x16x32_bf16(fr1, fr0, acc10, 0, 0, 0);
        acc11 = __builtin_amdgcn_mfma_f32_16x16x32_bf16(fr1, fr1, acc11, 0, 0, 0);
    }

    float* ob = out + (size_t)b * OUTW;

    // ---- bottom_mlp_out copy (coalesced) ----
    const float* bb = bottom + (size_t)b * ND;
    ob[lane]      = bb[lane];
    ob[lane + 64] = bb[lane + 64];

    // ---- tril scatter (direct; L2 write-combines the 1.9KB row region) ----
    const int jj = lane & 15;
    const int r0 = (lane >> 4) * 4;
    #pragma unroll
    for (int e = 0; e < 4; ++e) {
        int i0 = r0 + e;                       // tile (0,0): i 0..15, j 0..15
        if (jj < i0) ob[128 + (i0 * (i0 - 1)) / 2 + jj] = acc00[e];
        int i1 = i0 + 16;                      // tiles (1,0)/(1,1): i 16..26
        if (i1 < NF) {
            ob[128 + (i1 * (i1 - 1)) / 2 + jj] = acc10[e];          // j 0..15 < i
            int j1 = jj + 16;
            if (j1 < i1) ob[128 + (i1 * (i1 - 1)) / 2 + j1] = acc11[e];
        }
    }
}

extern "C" void kernel_launch(void* const* d_in, const int* in_sizes, int n_in,
                              void* d_out, int out_size, void* d_ws, size_t ws_size,
                              hipStream_t stream) {
    const float* feat   = (const float*)d_in[0];
    const float* bottom = (const float*)d_in[1];
    float* out          = (float*)d_out;
    const int B = in_sizes[0] / (NF * ND);
    const int grid = (B + WAVES - 1) / WAVES;
    dot_interact_kernel<<<grid, 256, 0, stream>>>(feat, bottom, out, B);
}